// Round 1
// baseline (529.320 us; speedup 1.0000x reference)
//
#include <hip/hip_runtime.h>

// ---------------------------------------------------------------------------
// SegAwareMultiHeadAttention on MI355X (gfx950)
// B=32, N=577, HIDDEN=768, HEADS=12, HEAD_DIM=64
// Pipeline: cast/transpose -> QKV GEMM (bf16 MFMA) -> flash attention -> proj GEMM
// ---------------------------------------------------------------------------

typedef unsigned short bf16_t;
typedef __attribute__((ext_vector_type(8))) short short8;   // 8 bf16 = 4 VGPRs (MFMA A/B frag)
typedef __attribute__((ext_vector_type(4))) float f32x4;    // MFMA C/D frag

#define B_    32
#define N_    577
#define BN_   18464      // B_*N_
#define HID_  768
#define NH_   12
#define HD_   64
#define QKVC_ 2304

// fp32 -> bf16 round-to-nearest-even (values here are well inside range; no NaN)
__device__ __forceinline__ bf16_t f2bf(float f) {
  union { float f; unsigned u; } x; x.f = f;
  unsigned r = x.u + 0x7fffu + ((x.u >> 16) & 1u);
  return (bf16_t)(r >> 16);
}

// ---------------------------------------------------------------------------
// Cast fp32 -> bf16, 4 elems/thread
// ---------------------------------------------------------------------------
__global__ __launch_bounds__(256) void cast_kernel(const float* __restrict__ in,
                                                   bf16_t* __restrict__ out, int n4) {
  int i = blockIdx.x * 256 + threadIdx.x;
  if (i >= n4) return;
  float4 v = ((const float4*)in)[i];
  ushort4 o;
  o.x = f2bf(v.x); o.y = f2bf(v.y); o.z = f2bf(v.z); o.w = f2bf(v.w);
  ((ushort4*)out)[i] = o;
}

// ---------------------------------------------------------------------------
// Transpose + cast: in fp32 [R][C] -> out bf16 [C][R].  R,C multiples of 32.
// ---------------------------------------------------------------------------
__global__ __launch_bounds__(256) void transpose_cast_kernel(const float* __restrict__ in,
                                                             bf16_t* __restrict__ out,
                                                             int R, int C) {
  __shared__ float tile[32][33];  // +1 pad: no bank conflicts
  int c0 = blockIdx.x * 32, r0 = blockIdx.y * 32;
  int tx = threadIdx.x, ty = threadIdx.y;
  #pragma unroll
  for (int i = ty; i < 32; i += 8)
    tile[i][tx] = in[(size_t)(r0 + i) * C + c0 + tx];
  __syncthreads();
  #pragma unroll
  for (int i = ty; i < 32; i += 8)
    out[(size_t)(c0 + i) * R + r0 + tx] = f2bf(tile[tx][i]);
}

// ---------------------------------------------------------------------------
// bf16 MFMA GEMM: C[M][Nc] = A[M][768] * Bt[Nc][768]^T + bias
// 128x128 tile, BK=32 (one 16x16x32 MFMA per K-tile per frag), 256 thr = 4 waves,
// wave -> 64x64 (4x4 frags). OUT_BF16: 1 -> bf16 out, 0 -> fp32 out.
// ---------------------------------------------------------------------------
template <int OUT_BF16>
__global__ __launch_bounds__(256) void gemm_bf16_kernel(
    const bf16_t* __restrict__ A,
    const bf16_t* __restrict__ Bt,
    const float* __restrict__ bias,
    void* __restrict__ Cout,
    int M, int Nc) {
  __shared__ bf16_t As[128 * 32];
  __shared__ bf16_t Bs[128 * 32];

  const int tid  = threadIdx.x;
  const int lane = tid & 63, w = tid >> 6;
  const int quad = lane >> 4, l16 = lane & 15;
  const int m0 = blockIdx.x * 128, n0 = blockIdx.y * 128;
  const int wm = (w >> 1) * 64, wn = (w & 1) * 64;

  f32x4 acc[4][4];
  #pragma unroll
  for (int i = 0; i < 4; ++i)
    #pragma unroll
    for (int j = 0; j < 4; ++j)
      acc[i][j] = (f32x4){0.f, 0.f, 0.f, 0.f};

  for (int kt = 0; kt < 768; kt += 32) {
    __syncthreads();  // protect previous iteration's LDS reads
    #pragma unroll
    for (int rr = 0; rr < 2; ++rr) {
      int idx = rr * 256 + tid;
      int row = idx >> 2, ch = idx & 3;           // row 0..127, 8-elem chunk 0..3
      uint4 va = {0u, 0u, 0u, 0u};
      int gm = m0 + row;
      if (gm < M) va = *(const uint4*)(A + (size_t)gm * 768 + kt + ch * 8);
      *(uint4*)(As + row * 32 + ch * 8) = va;
      int gn = n0 + row;                          // Nc multiple of 128: always valid
      uint4 vb = *(const uint4*)(Bt + (size_t)gn * 768 + kt + ch * 8);
      *(uint4*)(Bs + row * 32 + ch * 8) = vb;
    }
    __syncthreads();

    short8 af[4], bf[4];
    #pragma unroll
    for (int i = 0; i < 4; ++i)
      af[i] = *(const short8*)(As + (wm + i * 16 + l16) * 32 + quad * 8);
    #pragma unroll
    for (int j = 0; j < 4; ++j)
      bf[j] = *(const short8*)(Bs + (wn + j * 16 + l16) * 32 + quad * 8);
    #pragma unroll
    for (int i = 0; i < 4; ++i)
      #pragma unroll
      for (int j = 0; j < 4; ++j)
        acc[i][j] = __builtin_amdgcn_mfma_f32_16x16x32_bf16(af[i], bf[j], acc[i][j], 0, 0, 0);
  }

  // epilogue: C layout col=lane&15, row=quad*4+reg
  #pragma unroll
  for (int i = 0; i < 4; ++i) {
    int mrow_base = m0 + wm + i * 16 + quad * 4;
    #pragma unroll
    for (int j = 0; j < 4; ++j) {
      int col = n0 + wn + j * 16 + l16;
      float bs = bias[col];
      #pragma unroll
      for (int r = 0; r < 4; ++r) {
        int row = mrow_base + r;
        if (row < M) {
          float v = acc[i][j][r] + bs;
          if (OUT_BF16)
            ((bf16_t*)Cout)[(size_t)row * Nc + col] = f2bf(v);
          else
            ((float*)Cout)[(size_t)row * Nc + col] = v;
        }
      }
    }
  }
}

// ---------------------------------------------------------------------------
// Flash attention. Block = (q-tile of 64, head, batch), 256 thr = 4 waves,
// wave owns 16 query rows. KV tiles of 64 staged in LDS (V transposed, pitch 72).
// Online softmax in fp32 registers; P round-trips LDS (C-layout -> A-layout).
// seg bias added on the global query row 0 only, keys 1..576.
// ---------------------------------------------------------------------------
__global__ __launch_bounds__(256) void attn_kernel(
    const bf16_t* __restrict__ qkv,       // [BN][2304]  (q|k|v interleaved per row)
    const float* __restrict__ seg_bias,   // [B][576]
    const float* __restrict__ seg_scale,  // [1]
    bf16_t* __restrict__ out) {           // [BN][768]
  const int qt = blockIdx.x;   // 0..9
  const int h  = blockIdx.y;   // 0..11
  const int b  = blockIdx.z;   // 0..31
  const int tid  = threadIdx.x;
  const int w = tid >> 6, lane = tid & 63;
  const int quad = lane >> 4, l16 = lane & 15;

  __shared__ bf16_t Ks[64 * 64];      // [key][d]
  __shared__ bf16_t Vst[64 * 72];     // [d][key], pitch 72 (bank-conflict pad, 16B-aligned rows)
  __shared__ bf16_t Pb[4][16 * 64];   // per-wave P tile [qrow][key]

  const size_t baseq = ((size_t)b * N_) * QKVC_ + (size_t)h * HD_;
  const bf16_t* Qp = qkv + baseq;
  const bf16_t* Kp = qkv + baseq + HID_;
  const bf16_t* Vp = qkv + baseq + 2 * HID_;

  const int q0 = qt * 64;
  int qr = q0 + w * 16 + l16;
  int qrc = qr < N_ ? qr : (N_ - 1);   // clamp padded rows (computed, never stored)
  short8 qf[2];
  qf[0] = *(const short8*)(Qp + (size_t)qrc * QKVC_ + quad * 8);
  qf[1] = *(const short8*)(Qp + (size_t)qrc * QKVC_ + 32 + quad * 8);

  f32x4 o[4];
  float m_run[4], l_run[4];
  #pragma unroll
  for (int i = 0; i < 4; ++i) {
    o[i] = (f32x4){0.f, 0.f, 0.f, 0.f};
    m_run[i] = -3.0e38f;
    l_run[i] = 0.f;
  }

  const float ss = seg_scale[0];
  const bool bias_wave = (qt == 0 && w == 0);
  const int srow = tid >> 3;   // 0..31
  const int sch  = tid & 7;    // 0..7

  for (int t = 0; t < 10; ++t) {
    const int kv0 = t * 64;
    __syncthreads();  // WAR: previous iter's Ks/Vst/Pb reads done
    #pragma unroll
    for (int rr = 0; rr < 2; ++rr) {
      int row = rr * 32 + srow;
      int krow = kv0 + row;
      if (krow > N_ - 1) krow = N_ - 1;  // clamped keys get masked below
      *(uint4*)(Ks + row * 64 + sch * 8) =
          *(const uint4*)(Kp + (size_t)krow * QKVC_ + sch * 8);
      short8 v8 = *(const short8*)(Vp + (size_t)krow * QKVC_ + sch * 8);
      #pragma unroll
      for (int j = 0; j < 8; ++j)
        Vst[(sch * 8 + j) * 72 + row] = (bf16_t)v8[j];
    }
    __syncthreads();

    // S = Q K^T  (4 key-subtiles of 16)
    f32x4 s[4];
    #pragma unroll
    for (int sub = 0; sub < 4; ++sub) {
      short8 k0 = *(const short8*)(Ks + (sub * 16 + l16) * 64 + quad * 8);
      short8 k1 = *(const short8*)(Ks + (sub * 16 + l16) * 64 + 32 + quad * 8);
      f32x4 c = (f32x4){0.f, 0.f, 0.f, 0.f};
      c = __builtin_amdgcn_mfma_f32_16x16x32_bf16(qf[0], k0, c, 0, 0, 0);
      c = __builtin_amdgcn_mfma_f32_16x16x32_bf16(qf[1], k1, c, 0, 0, 0);
      s[sub] = c;
    }

    // scale + CLS-row bias + key mask
    #pragma unroll
    for (int sub = 0; sub < 4; ++sub) {
      int key = kv0 + sub * 16 + l16;
      #pragma unroll
      for (int r = 0; r < 4; ++r) {
        float v = s[sub][r] * 0.125f;
        if (bias_wave && quad == 0 && r == 0 && key >= 1 && key < N_)
          v += seg_bias[b * (N_ - 1) + key - 1] * ss;
        if (key >= N_) v = -3.0e38f;
        s[sub][r] = v;
      }
    }

    // per-row tile max (reduce across the 16 lanes of the quad)
    float mt[4];
    #pragma unroll
    for (int r = 0; r < 4; ++r) {
      float m = fmaxf(fmaxf(s[0][r], s[1][r]), fmaxf(s[2][r], s[3][r]));
      #pragma unroll
      for (int off = 1; off < 16; off <<= 1)
        m = fmaxf(m, __shfl_xor(m, off));
      mt[r] = m;
    }

    float alpha[4];
    #pragma unroll
    for (int r = 0; r < 4; ++r) {
      float mnew = fmaxf(m_run[r], mt[r]);
      alpha[r] = exp2f((m_run[r] - mnew) * 1.44269504f);
      m_run[r] = mnew;
    }

    float lt[4] = {0.f, 0.f, 0.f, 0.f};
    #pragma unroll
    for (int sub = 0; sub < 4; ++sub)
      #pragma unroll
      for (int r = 0; r < 4; ++r) {
        float p = exp2f((s[sub][r] - m_run[r]) * 1.44269504f);
        s[sub][r] = p;
        lt[r] += p;
      }
    #pragma unroll
    for (int r = 0; r < 4; ++r) {
      #pragma unroll
      for (int off = 1; off < 16; off <<= 1)
        lt[r] += __shfl_xor(lt[r], off);
      l_run[r] = l_run[r] * alpha[r] + lt[r];
    }
    #pragma unroll
    for (int ds = 0; ds < 4; ++ds)
      #pragma unroll
      for (int r = 0; r < 4; ++r)
        o[ds][r] *= alpha[r];

    // P -> LDS (C-layout write), re-read as A-layout frags
    bf16_t* pb = Pb[w];
    #pragma unroll
    for (int sub = 0; sub < 4; ++sub)
      #pragma unroll
      for (int r = 0; r < 4; ++r)
        pb[(quad * 4 + r) * 64 + sub * 16 + l16] = f2bf(s[sub][r]);
    __syncthreads();

    short8 pa0 = *(const short8*)(pb + l16 * 64 + quad * 8);        // keys 0..31
    short8 pa1 = *(const short8*)(pb + l16 * 64 + 32 + quad * 8);   // keys 32..63
    #pragma unroll
    for (int ds = 0; ds < 4; ++ds) {
      short8 vb0 = *(const short8*)(Vst + (ds * 16 + l16) * 72 + quad * 8);
      short8 vb1 = *(const short8*)(Vst + (ds * 16 + l16) * 72 + 32 + quad * 8);
      o[ds] = __builtin_amdgcn_mfma_f32_16x16x32_bf16(pa0, vb0, o[ds], 0, 0, 0);
      o[ds] = __builtin_amdgcn_mfma_f32_16x16x32_bf16(pa1, vb1, o[ds], 0, 0, 0);
    }
  }

  // epilogue: O /= l, write bf16 [b*N+row][h*64+d]
  #pragma unroll
  for (int r = 0; r < 4; ++r) {
    int row = q0 + w * 16 + quad * 4 + r;
    if (row < N_) {
      float inv = 1.0f / l_run[r];
      size_t base = ((size_t)b * N_ + row) * HID_ + h * HD_;
      #pragma unroll
      for (int ds = 0; ds < 4; ++ds)
        out[base + ds * 16 + l16] = f2bf(o[ds][r] * inv);
    }
  }
}

// ---------------------------------------------------------------------------
// kernel_launch
// ws layout (bytes):
//   xb     bf16[BN*768]    @ 0          (28,360,704)  -- reused as attnb after QKV GEMM
//   wqkvT  bf16[2304*768]  @ 28,360,704 ( 3,538,944)
//   wprojT bf16[768*768]   @ 31,899,648 ( 1,179,648)
//   qkvb   bf16[BN*2304]   @ 33,079,296 (85,082,112)
//   total 118,161,408 B
// ---------------------------------------------------------------------------
extern "C" void kernel_launch(void* const* d_in, const int* in_sizes, int n_in,
                              void* d_out, int out_size, void* d_ws, size_t ws_size,
                              hipStream_t stream) {
  const float* x         = (const float*)d_in[0];
  const float* seg_bias  = (const float*)d_in[1];
  const float* w_qkv     = (const float*)d_in[2];
  const float* b_qkv     = (const float*)d_in[3];
  const float* w_proj    = (const float*)d_in[4];
  const float* b_proj    = (const float*)d_in[5];
  const float* seg_scale = (const float*)d_in[6];

  char* ws = (char*)d_ws;
  bf16_t* xb     = (bf16_t*)ws;
  bf16_t* wqkvT  = (bf16_t*)(ws + 28360704);
  bf16_t* wprojT = (bf16_t*)(ws + 28360704 + 3538944);
  bf16_t* qkvb   = (bf16_t*)(ws + 28360704 + 3538944 + 1179648);
  bf16_t* attnb  = xb;  // reuse: x_bf16 dead after QKV GEMM

  // 1) casts / transposes
  cast_kernel<<<(BN_ * HID_ / 4) / 256, 256, 0, stream>>>(x, xb, BN_ * HID_ / 4);
  dim3 tb(32, 8);
  transpose_cast_kernel<<<dim3(QKVC_ / 32, HID_ / 32), tb, 0, stream>>>(w_qkv, wqkvT, HID_, QKVC_);
  transpose_cast_kernel<<<dim3(HID_ / 32, HID_ / 32), tb, 0, stream>>>(w_proj, wprojT, HID_, HID_);

  // 2) QKV projection: [18464][768] x [768][2304] -> bf16 qkv
  gemm_bf16_kernel<1><<<dim3(145, QKVC_ / 128), 256, 0, stream>>>(
      xb, wqkvT, b_qkv, (void*)qkvb, BN_, QKVC_);

  // 3) attention
  attn_kernel<<<dim3(10, NH_, B_), 256, 0, stream>>>(qkvb, seg_bias, seg_scale, attnb);

  // 4) output projection: [18464][768] x [768][768] -> fp32 d_out
  gemm_bf16_kernel<0><<<dim3(145, HID_ / 128), 256, 0, stream>>>(
      attnb, wprojT, b_proj, d_out, BN_, HID_);
}

// Round 2
// 446.332 us; speedup vs baseline: 1.1859x; 1.1859x over previous
//
#include <hip/hip_runtime.h>

// ---------------------------------------------------------------------------
// SegAwareMultiHeadAttention on MI355X (gfx950)
// B=32, N=577, HIDDEN=768, HEADS=12, HEAD_DIM=64
// cast/transpose -> QKV GEMM (bf16 MFMA) -> V-transpose prepass ->
// flash attention (Q-tile 128, pitch-72 LDS) -> proj GEMM
// ---------------------------------------------------------------------------

typedef unsigned short bf16_t;
typedef __attribute__((ext_vector_type(8))) short short8;   // 8 bf16 = 16 B
typedef __attribute__((ext_vector_type(4))) float f32x4;    // MFMA C/D frag

#define B_    32
#define N_    577
#define BN_   18464
#define HID_  768
#define NH_   12
#define HD_   64
#define QKVC_ 2304
#define NPAD_ 640     // keys padded to 10 tiles of 64

__device__ __forceinline__ bf16_t f2bf(float f) {
  union { float f; unsigned u; } x; x.f = f;
  unsigned r = x.u + 0x7fffu + ((x.u >> 16) & 1u);
  return (bf16_t)(r >> 16);
}

// ---------------------------------------------------------------------------
__global__ __launch_bounds__(256) void cast_kernel(const float* __restrict__ in,
                                                   bf16_t* __restrict__ out, int n4) {
  int i = blockIdx.x * 256 + threadIdx.x;
  if (i >= n4) return;
  float4 v = ((const float4*)in)[i];
  ushort4 o;
  o.x = f2bf(v.x); o.y = f2bf(v.y); o.z = f2bf(v.z); o.w = f2bf(v.w);
  ((ushort4*)out)[i] = o;
}

// in fp32 [R][C] -> out bf16 [C][R]
__global__ __launch_bounds__(256) void transpose_cast_kernel(const float* __restrict__ in,
                                                             bf16_t* __restrict__ out,
                                                             int R, int C) {
  __shared__ float tile[32][33];
  int c0 = blockIdx.x * 32, r0 = blockIdx.y * 32;
  int tx = threadIdx.x, ty = threadIdx.y;
  #pragma unroll
  for (int i = ty; i < 32; i += 8)
    tile[i][tx] = in[(size_t)(r0 + i) * C + c0 + tx];
  __syncthreads();
  #pragma unroll
  for (int i = ty; i < 32; i += 8)
    out[(size_t)(c0 + i) * R + r0 + tx] = f2bf(tile[tx][i]);
}

// ---------------------------------------------------------------------------
// GEMM: C[M][Nc] = A[M][768] * Bt[Nc][768]^T + bias. 128x128 tile, BK=32.
// LDS pitch 40 (odd multiple of 4 dwords -> uniform bank spread for b128).
// ---------------------------------------------------------------------------
template <int OUT_BF16>
__global__ __launch_bounds__(256) void gemm_bf16_kernel(
    const bf16_t* __restrict__ A,
    const bf16_t* __restrict__ Bt,
    const float* __restrict__ bias,
    void* __restrict__ Cout,
    int M, int Nc) {
  __shared__ bf16_t As[128 * 40];
  __shared__ bf16_t Bs[128 * 40];

  const int tid  = threadIdx.x;
  const int lane = tid & 63, w = tid >> 6;
  const int quad = lane >> 4, l16 = lane & 15;
  const int m0 = blockIdx.x * 128, n0 = blockIdx.y * 128;
  const int wm = (w >> 1) * 64, wn = (w & 1) * 64;

  f32x4 acc[4][4];
  #pragma unroll
  for (int i = 0; i < 4; ++i)
    #pragma unroll
    for (int j = 0; j < 4; ++j)
      acc[i][j] = (f32x4){0.f, 0.f, 0.f, 0.f};

  for (int kt = 0; kt < 768; kt += 32) {
    __syncthreads();
    #pragma unroll
    for (int rr = 0; rr < 2; ++rr) {
      int idx = rr * 256 + tid;
      int row = idx >> 2, ch = idx & 3;
      short8 va = (short8)(short)0;
      int gm = m0 + row;
      if (gm < M) va = *(const short8*)(A + (size_t)gm * 768 + kt + ch * 8);
      *(short8*)(As + row * 40 + ch * 8) = va;
      int gn = n0 + row;
      short8 vb = *(const short8*)(Bt + (size_t)gn * 768 + kt + ch * 8);
      *(short8*)(Bs + row * 40 + ch * 8) = vb;
    }
    __syncthreads();

    short8 af[4], bf[4];
    #pragma unroll
    for (int i = 0; i < 4; ++i)
      af[i] = *(const short8*)(As + (wm + i * 16 + l16) * 40 + quad * 8);
    #pragma unroll
    for (int j = 0; j < 4; ++j)
      bf[j] = *(const short8*)(Bs + (wn + j * 16 + l16) * 40 + quad * 8);
    #pragma unroll
    for (int i = 0; i < 4; ++i)
      #pragma unroll
      for (int j = 0; j < 4; ++j)
        acc[i][j] = __builtin_amdgcn_mfma_f32_16x16x32_bf16(af[i], bf[j], acc[i][j], 0, 0, 0);
  }

  #pragma unroll
  for (int i = 0; i < 4; ++i) {
    int mrow_base = m0 + wm + i * 16 + quad * 4;
    #pragma unroll
    for (int j = 0; j < 4; ++j) {
      int col = n0 + wn + j * 16 + l16;
      float bs = bias[col];
      #pragma unroll
      for (int r = 0; r < 4; ++r) {
        int row = mrow_base + r;
        if (row < M) {
          float v = acc[i][j][r] + bs;
          if (OUT_BF16)
            ((bf16_t*)Cout)[(size_t)row * Nc + col] = f2bf(v);
          else
            ((float*)Cout)[(size_t)row * Nc + col] = v;
        }
      }
    }
  }
}

// ---------------------------------------------------------------------------
// V transpose prepass: qkv V-slice [key][d] -> vT[bh][d=64][NPAD_ keys]
// LDS pitch 65: both scalar sides ~2-way (free).
// ---------------------------------------------------------------------------
__global__ __launch_bounds__(256) void vt_kernel(const bf16_t* __restrict__ qkv,
                                                 bf16_t* __restrict__ vT) {
  const int t = blockIdx.x, h = blockIdx.y, b = blockIdx.z;
  const int tid = threadIdx.x;
  __shared__ bf16_t Ls[64 * 65];
  const int kv0 = t * 64;
  const bf16_t* Vp = qkv + (size_t)b * N_ * QKVC_ + 2 * HID_ + h * HD_;

  #pragma unroll
  for (int it = 0; it < 2; ++it) {
    int idx = it * 256 + tid;
    int row = idx >> 3, ch = idx & 7;
    int krow = kv0 + row; if (krow > N_ - 1) krow = N_ - 1;
    short8 v8 = *(const short8*)(Vp + (size_t)krow * QKVC_ + ch * 8);
    #pragma unroll
    for (int j = 0; j < 8; ++j)
      Ls[(ch * 8 + j) * 65 + row] = (bf16_t)v8[j];
  }
  __syncthreads();
  bf16_t* outp = vT + ((size_t)(b * NH_ + h) * HD_) * NPAD_;
  #pragma unroll
  for (int it = 0; it < 2; ++it) {
    int idx = it * 256 + tid;
    int d = idx >> 3, kc = idx & 7;
    short8 o8;
    #pragma unroll
    for (int j = 0; j < 8; ++j)
      o8[j] = (short)Ls[d * 65 + kc * 8 + j];
    *(short8*)(outp + (size_t)d * NPAD_ + kv0 + kc * 8) = o8;
  }
}

// ---------------------------------------------------------------------------
// Flash attention v2. Block = (q-tile 128, head, batch), 4 waves x 32 q-rows.
// KV tile 64. LDS: Ks[64][72], Vt[64][72] ([d][key]), P per-wave [32][72].
// Max-free softmax (scores bounded): no shuffles in loop, l-reduce at end.
// ---------------------------------------------------------------------------
__global__ __launch_bounds__(256) void attn_kernel(
    const bf16_t* __restrict__ qkv,       // [BN][2304]
    const bf16_t* __restrict__ vT,        // [bh][64][NPAD_]
    const float* __restrict__ seg_bias,   // [B][576]
    const float* __restrict__ seg_scale,  // [1]
    bf16_t* __restrict__ out) {           // [BN][768]
  const int qt = blockIdx.x;   // 0..4
  const int h  = blockIdx.y;
  const int b  = blockIdx.z;
  const int tid = threadIdx.x;
  const int w = tid >> 6, lane = tid & 63;
  const int quad = lane >> 4, l16 = lane & 15;

  __shared__ bf16_t Ks[64 * 72];
  __shared__ bf16_t Vt[64 * 72];
  __shared__ bf16_t Pb[4][32 * 72];

  const bf16_t* Qbase = qkv + (size_t)b * N_ * QKVC_ + h * HD_;
  const bf16_t* Kbase = Qbase + HID_;
  const bf16_t* Vtb   = vT + ((size_t)(b * NH_ + h) * HD_) * NPAD_;

  const int q0 = qt * 128 + w * 32;
  short8 qf[2][2];
  #pragma unroll
  for (int mi = 0; mi < 2; ++mi) {
    int qr = q0 + mi * 16 + l16;
    if (qr > N_ - 1) qr = N_ - 1;
    qf[mi][0] = *(const short8*)(Qbase + (size_t)qr * QKVC_ + quad * 8);
    qf[mi][1] = *(const short8*)(Qbase + (size_t)qr * QKVC_ + 32 + quad * 8);
  }

  f32x4 o[2][4];
  float lsum[2][4];
  #pragma unroll
  for (int mi = 0; mi < 2; ++mi)
    #pragma unroll
    for (int j = 0; j < 4; ++j) {
      o[mi][j] = (f32x4){0.f, 0.f, 0.f, 0.f};
      lsum[mi][j] = 0.f;
    }

  const float ss = seg_scale[0] * 1.44269504f;
  const bool bias_wave = (qt == 0 && w == 0);
  bf16_t* pw = Pb[w];

  for (int t = 0; t < 10; ++t) {
    const int kv0 = t * 64;
    __syncthreads();  // prior tile's LDS reads done
    #pragma unroll
    for (int it = 0; it < 2; ++it) {
      int idx = it * 256 + tid;
      int row = idx >> 3, ch = idx & 7;
      int krow = kv0 + row; if (krow > N_ - 1) krow = N_ - 1;
      short8 k8 = *(const short8*)(Kbase + (size_t)krow * QKVC_ + ch * 8);
      *(short8*)(Ks + row * 72 + ch * 8) = k8;
      short8 v8 = *(const short8*)(Vtb + (size_t)row * NPAD_ + kv0 + ch * 8);
      *(short8*)(Vt + row * 72 + ch * 8) = v8;
    }
    __syncthreads();

    // S = Q K^T
    f32x4 s[2][4];
    #pragma unroll
    for (int mi = 0; mi < 2; ++mi)
      #pragma unroll
      for (int sub = 0; sub < 4; ++sub)
        s[mi][sub] = (f32x4){0.f, 0.f, 0.f, 0.f};
    #pragma unroll
    for (int sub = 0; sub < 4; ++sub) {
      short8 k0 = *(const short8*)(Ks + (sub * 16 + l16) * 72 + quad * 8);
      short8 k1 = *(const short8*)(Ks + (sub * 16 + l16) * 72 + 32 + quad * 8);
      #pragma unroll
      for (int mi = 0; mi < 2; ++mi) {
        s[mi][sub] = __builtin_amdgcn_mfma_f32_16x16x32_bf16(qf[mi][0], k0, s[mi][sub], 0, 0, 0);
        s[mi][sub] = __builtin_amdgcn_mfma_f32_16x16x32_bf16(qf[mi][1], k1, s[mi][sub], 0, 0, 0);
      }
    }

    // softmax (no running max; scores bounded) + P write
    #pragma unroll
    for (int mi = 0; mi < 2; ++mi)
      #pragma unroll
      for (int sub = 0; sub < 4; ++sub) {
        int key = kv0 + sub * 16 + l16;
        #pragma unroll
        for (int r = 0; r < 4; ++r) {
          float v = s[mi][sub][r] * 0.180336881f;  // *scale*log2(e)
          if (bias_wave && mi == 0 && quad == 0 && r == 0 && key >= 1 && key < N_)
            v += seg_bias[b * (N_ - 1) + key - 1] * ss;
          float p = exp2f(v);
          if (key >= N_) p = 0.f;
          lsum[mi][r] += p;
          pw[(mi * 16 + quad * 4 + r) * 72 + sub * 16 + l16] = f2bf(p);
        }
      }

    // PV (P write->read is same-wave: LDS ops per-wave in order)
    #pragma unroll
    for (int mi = 0; mi < 2; ++mi) {
      short8 pa0 = *(const short8*)(pw + (mi * 16 + l16) * 72 + quad * 8);
      short8 pa1 = *(const short8*)(pw + (mi * 16 + l16) * 72 + 32 + quad * 8);
      #pragma unroll
      for (int ds = 0; ds < 4; ++ds) {
        short8 vb0 = *(const short8*)(Vt + (ds * 16 + l16) * 72 + quad * 8);
        short8 vb1 = *(const short8*)(Vt + (ds * 16 + l16) * 72 + 32 + quad * 8);
        o[mi][ds] = __builtin_amdgcn_mfma_f32_16x16x32_bf16(pa0, vb0, o[mi][ds], 0, 0, 0);
        o[mi][ds] = __builtin_amdgcn_mfma_f32_16x16x32_bf16(pa1, vb1, o[mi][ds], 0, 0, 0);
      }
    }
  }

  // epilogue
  #pragma unroll
  for (int mi = 0; mi < 2; ++mi)
    #pragma unroll
    for (int r = 0; r < 4; ++r) {
      float l = lsum[mi][r];
      #pragma unroll
      for (int off = 1; off < 16; off <<= 1)
        l += __shfl_xor(l, off);
      float inv = 1.0f / l;
      int row = q0 + mi * 16 + quad * 4 + r;
      if (row < N_) {
        size_t base = ((size_t)b * N_ + row) * HID_ + h * HD_;
        #pragma unroll
        for (int ds = 0; ds < 4; ++ds)
          out[base + ds * 16 + l16] = f2bf(o[mi][ds][r] * inv);
      }
    }
}

// ---------------------------------------------------------------------------
// ws layout (bytes):
//   xb     bf16[BN*768]     @ 0            (28,360,704)  -- reused as attnb
//   wqkvT  bf16[2304*768]   @ 28,360,704   ( 3,538,944)
//   wprojT bf16[768*768]    @ 31,899,648   ( 1,179,648)
//   qkvb   bf16[BN*2304]    @ 33,079,296   (85,082,112)
//   vT     bf16[384*64*640] @ 118,161,408  (31,457,280)
//   total 149,618,688 B
// ---------------------------------------------------------------------------
extern "C" void kernel_launch(void* const* d_in, const int* in_sizes, int n_in,
                              void* d_out, int out_size, void* d_ws, size_t ws_size,
                              hipStream_t stream) {
  const float* x         = (const float*)d_in[0];
  const float* seg_bias  = (const float*)d_in[1];
  const float* w_qkv     = (const float*)d_in[2];
  const float* b_qkv     = (const float*)d_in[3];
  const float* w_proj    = (const float*)d_in[4];
  const float* b_proj    = (const float*)d_in[5];
  const float* seg_scale = (const float*)d_in[6];

  char* ws = (char*)d_ws;
  bf16_t* xb     = (bf16_t*)ws;
  bf16_t* wqkvT  = (bf16_t*)(ws + 28360704);
  bf16_t* wprojT = (bf16_t*)(ws + 31899648);
  bf16_t* qkvb   = (bf16_t*)(ws + 33079296);
  bf16_t* vT     = (bf16_t*)(ws + 118161408);
  bf16_t* attnb  = xb;

  cast_kernel<<<(BN_ * HID_ / 4) / 256, 256, 0, stream>>>(x, xb, BN_ * HID_ / 4);
  dim3 tb(32, 8);
  transpose_cast_kernel<<<dim3(QKVC_ / 32, HID_ / 32), tb, 0, stream>>>(w_qkv, wqkvT, HID_, QKVC_);
  transpose_cast_kernel<<<dim3(HID_ / 32, HID_ / 32), tb, 0, stream>>>(w_proj, wprojT, HID_, HID_);

  gemm_bf16_kernel<1><<<dim3(145, QKVC_ / 128), 256, 0, stream>>>(
      xb, wqkvT, b_qkv, (void*)qkvb, BN_, QKVC_);

  vt_kernel<<<dim3(10, NH_, B_), 256, 0, stream>>>(qkvb, vT);

  attn_kernel<<<dim3(5, NH_, B_), 256, 0, stream>>>(qkvb, vT, seg_bias, seg_scale, attnb);

  gemm_bf16_kernel<0><<<dim3(145, HID_ / 128), 256, 0, stream>>>(
      attnb, wprojT, b_proj, d_out, BN_, HID_);
}

// Round 3
// 422.973 us; speedup vs baseline: 1.2514x; 1.0552x over previous
//
#include <hip/hip_runtime.h>

// ---------------------------------------------------------------------------
// SegAwareMultiHeadAttention on MI355X (gfx950)
// B=32, N=577, HIDDEN=768, HEADS=12, HEAD_DIM=64
// cast/transpose -> QKV GEMM (bf16 MFMA, global_load_lds staging) ->
// V-transpose prepass -> flash attention (Q-tile 128) -> proj GEMM
// ---------------------------------------------------------------------------

typedef unsigned short bf16_t;
typedef __attribute__((ext_vector_type(8))) short short8;   // 8 bf16 = 16 B
typedef __attribute__((ext_vector_type(4))) float f32x4;    // MFMA C/D frag

#define B_    32
#define N_    577
#define BN_   18464
#define HID_  768
#define NH_   12
#define HD_   64
#define QKVC_ 2304
#define NPAD_ 640     // keys padded to 10 tiles of 64

__device__ __forceinline__ bf16_t f2bf(float f) {
  union { float f; unsigned u; } x; x.f = f;
  unsigned r = x.u + 0x7fffu + ((x.u >> 16) & 1u);
  return (bf16_t)(r >> 16);
}

// ---------------------------------------------------------------------------
__global__ __launch_bounds__(256) void cast_kernel(const float* __restrict__ in,
                                                   bf16_t* __restrict__ out, int n4) {
  int i = blockIdx.x * 256 + threadIdx.x;
  if (i >= n4) return;
  float4 v = ((const float4*)in)[i];
  ushort4 o;
  o.x = f2bf(v.x); o.y = f2bf(v.y); o.z = f2bf(v.z); o.w = f2bf(v.w);
  ((ushort4*)out)[i] = o;
}

// in fp32 [R][C] -> out bf16 [C][R]
__global__ __launch_bounds__(256) void transpose_cast_kernel(const float* __restrict__ in,
                                                             bf16_t* __restrict__ out,
                                                             int R, int C) {
  __shared__ float tile[32][33];
  int c0 = blockIdx.x * 32, r0 = blockIdx.y * 32;
  int tx = threadIdx.x, ty = threadIdx.y;
  #pragma unroll
  for (int i = ty; i < 32; i += 8)
    tile[i][tx] = in[(size_t)(r0 + i) * C + c0 + tx];
  __syncthreads();
  #pragma unroll
  for (int i = ty; i < 32; i += 8)
    out[(size_t)(c0 + i) * R + r0 + tx] = f2bf(tile[tx][i]);
}

// ---------------------------------------------------------------------------
// GEMM: C[M][Nc] = A[M][768] * Bt[Nc][768]^T + bias. 128x128 tile, BK=32.
// Staging via global_load_lds width=16 (direct HBM->LDS DMA, no VGPR trip).
// LDS layout is XOR-swizzled at 16B-granule level:
//   granule(row, ch) stored at index row*4 + (ch ^ ((row>>1)&3))
// -> DMA lane-contiguity satisfied, global reads stay 64B-contiguous per row,
//    b128 frag reads spread over 8 distinct 4-bank groups (2-way = free).
// ---------------------------------------------------------------------------
template <int OUT_BF16>
__global__ __launch_bounds__(256) void gemm_bf16_kernel(
    const bf16_t* __restrict__ A,
    const bf16_t* __restrict__ Bt,
    const float* __restrict__ bias,
    void* __restrict__ Cout,
    int M, int Nc) {
  __shared__ bf16_t As[128 * 32];
  __shared__ bf16_t Bs[128 * 32];

  const int tid  = threadIdx.x;
  const int lane = tid & 63, w = tid >> 6;
  const int quad = lane >> 4, l16 = lane & 15;
  const int m0 = blockIdx.x * 128, n0 = blockIdx.y * 128;
  const int wm = (w >> 1) * 64, wn = (w & 1) * 64;

  // staging descriptors: granule gi = it*256+tid -> (row, source chunk)
  int s_row[2], s_ch[2];
  #pragma unroll
  for (int it = 0; it < 2; ++it) {
    int gi = it * 256 + tid;
    int row = gi >> 2, chp = gi & 3;
    s_row[it] = row;
    s_ch[it]  = chp ^ ((row >> 1) & 3);
  }

  f32x4 acc[4][4];
  #pragma unroll
  for (int i = 0; i < 4; ++i)
    #pragma unroll
    for (int j = 0; j < 4; ++j)
      acc[i][j] = (f32x4){0.f, 0.f, 0.f, 0.f};

  for (int kt = 0; kt < 768; kt += 32) {
    __syncthreads();  // WAR: prior iteration's frag reads done
    #pragma unroll
    for (int it = 0; it < 2; ++it) {
      int gi = it * 256 + tid;
      int row = s_row[it], ch = s_ch[it];
      int gm = m0 + row; if (gm >= M) gm = M - 1;  // dup rows, masked at epilogue
      __builtin_amdgcn_global_load_lds(
          (const __attribute__((address_space(1))) unsigned int*)(A + (size_t)gm * 768 + kt + ch * 8),
          (__attribute__((address_space(3))) unsigned int*)(As + gi * 8),
          16, 0, 0);
      int gn = n0 + row;  // Nc multiple of 128: always valid
      __builtin_amdgcn_global_load_lds(
          (const __attribute__((address_space(1))) unsigned int*)(Bt + (size_t)gn * 768 + kt + ch * 8),
          (__attribute__((address_space(3))) unsigned int*)(Bs + gi * 8),
          16, 0, 0);
    }
    __syncthreads();  // includes vmcnt(0) drain of the DMA

    short8 af[4], bfr[4];
    #pragma unroll
    for (int i = 0; i < 4; ++i) {
      int row = wm + i * 16 + l16;
      af[i] = *(const short8*)(As + row * 32 + (quad ^ ((row >> 1) & 3)) * 8);
    }
    #pragma unroll
    for (int j = 0; j < 4; ++j) {
      int row = wn + j * 16 + l16;
      bfr[j] = *(const short8*)(Bs + row * 32 + (quad ^ ((row >> 1) & 3)) * 8);
    }
    #pragma unroll
    for (int i = 0; i < 4; ++i)
      #pragma unroll
      for (int j = 0; j < 4; ++j)
        acc[i][j] = __builtin_amdgcn_mfma_f32_16x16x32_bf16(af[i], bfr[j], acc[i][j], 0, 0, 0);
  }

  // epilogue: C layout col=lane&15, row=quad*4+reg
  #pragma unroll
  for (int i = 0; i < 4; ++i) {
    int mrow_base = m0 + wm + i * 16 + quad * 4;
    #pragma unroll
    for (int j = 0; j < 4; ++j) {
      int col = n0 + wn + j * 16 + l16;
      float bs = bias[col];
      #pragma unroll
      for (int r = 0; r < 4; ++r) {
        int row = mrow_base + r;
        if (row < M) {
          float v = acc[i][j][r] + bs;
          if (OUT_BF16)
            ((bf16_t*)Cout)[(size_t)row * Nc + col] = f2bf(v);
          else
            ((float*)Cout)[(size_t)row * Nc + col] = v;
        }
      }
    }
  }
}

// ---------------------------------------------------------------------------
// V transpose prepass: qkv V-slice [key][d] -> vT[bh][d=64][NPAD_ keys]
// ---------------------------------------------------------------------------
__global__ __launch_bounds__(256) void vt_kernel(const bf16_t* __restrict__ qkv,
                                                 bf16_t* __restrict__ vT) {
  const int t = blockIdx.x, h = blockIdx.y, b = blockIdx.z;
  const int tid = threadIdx.x;
  __shared__ bf16_t Ls[64 * 65];
  const int kv0 = t * 64;
  const bf16_t* Vp = qkv + (size_t)b * N_ * QKVC_ + 2 * HID_ + h * HD_;

  #pragma unroll
  for (int it = 0; it < 2; ++it) {
    int idx = it * 256 + tid;
    int row = idx >> 3, ch = idx & 7;
    int krow = kv0 + row; if (krow > N_ - 1) krow = N_ - 1;
    short8 v8 = *(const short8*)(Vp + (size_t)krow * QKVC_ + ch * 8);
    #pragma unroll
    for (int j = 0; j < 8; ++j)
      Ls[(ch * 8 + j) * 65 + row] = (bf16_t)v8[j];
  }
  __syncthreads();
  bf16_t* outp = vT + ((size_t)(b * NH_ + h) * HD_) * NPAD_;
  #pragma unroll
  for (int it = 0; it < 2; ++it) {
    int idx = it * 256 + tid;
    int d = idx >> 3, kc = idx & 7;
    short8 o8;
    #pragma unroll
    for (int j = 0; j < 8; ++j)
      o8[j] = (short)Ls[d * 65 + kc * 8 + j];
    *(short8*)(outp + (size_t)d * NPAD_ + kv0 + kc * 8) = o8;
  }
}

// ---------------------------------------------------------------------------
// Flash attention v2. Block = (q-tile 128, head, batch), 4 waves x 32 q-rows.
// KV tile 64. LDS: Ks[64][72], Vt[64][72] ([d][key]), P per-wave [32][72].
// Max-free softmax (scores bounded): no shuffles in loop, l-reduce at end.
// ---------------------------------------------------------------------------
__global__ __launch_bounds__(256) void attn_kernel(
    const bf16_t* __restrict__ qkv,       // [BN][2304]
    const bf16_t* __restrict__ vT,        // [bh][64][NPAD_]
    const float* __restrict__ seg_bias,   // [B][576]
    const float* __restrict__ seg_scale,  // [1]
    bf16_t* __restrict__ out) {           // [BN][768]
  const int qt = blockIdx.x;   // 0..4
  const int h  = blockIdx.y;
  const int b  = blockIdx.z;
  const int tid = threadIdx.x;
  const int w = tid >> 6, lane = tid & 63;
  const int quad = lane >> 4, l16 = lane & 15;

  __shared__ bf16_t Ks[64 * 72];
  __shared__ bf16_t Vt[64 * 72];
  __shared__ bf16_t Pb[4][32 * 72];

  const bf16_t* Qbase = qkv + (size_t)b * N_ * QKVC_ + h * HD_;
  const bf16_t* Kbase = Qbase + HID_;
  const bf16_t* Vtb   = vT + ((size_t)(b * NH_ + h) * HD_) * NPAD_;

  const int q0 = qt * 128 + w * 32;
  short8 qf[2][2];
  #pragma unroll
  for (int mi = 0; mi < 2; ++mi) {
    int qr = q0 + mi * 16 + l16;
    if (qr > N_ - 1) qr = N_ - 1;
    qf[mi][0] = *(const short8*)(Qbase + (size_t)qr * QKVC_ + quad * 8);
    qf[mi][1] = *(const short8*)(Qbase + (size_t)qr * QKVC_ + 32 + quad * 8);
  }

  f32x4 o[2][4];
  float lsum[2][4];
  #pragma unroll
  for (int mi = 0; mi < 2; ++mi)
    #pragma unroll
    for (int j = 0; j < 4; ++j) {
      o[mi][j] = (f32x4){0.f, 0.f, 0.f, 0.f};
      lsum[mi][j] = 0.f;
    }

  const float ss = seg_scale[0] * 1.44269504f;
  const bool bias_wave = (qt == 0 && w == 0);
  bf16_t* pw = Pb[w];

  for (int t = 0; t < 10; ++t) {
    const int kv0 = t * 64;
    __syncthreads();  // prior tile's LDS reads done
    #pragma unroll
    for (int it = 0; it < 2; ++it) {
      int idx = it * 256 + tid;
      int row = idx >> 3, ch = idx & 7;
      int krow = kv0 + row; if (krow > N_ - 1) krow = N_ - 1;
      short8 k8 = *(const short8*)(Kbase + (size_t)krow * QKVC_ + ch * 8);
      *(short8*)(Ks + row * 72 + ch * 8) = k8;
      short8 v8 = *(const short8*)(Vtb + (size_t)row * NPAD_ + kv0 + ch * 8);
      *(short8*)(Vt + row * 72 + ch * 8) = v8;
    }
    __syncthreads();

    // S = Q K^T
    f32x4 s[2][4];
    #pragma unroll
    for (int mi = 0; mi < 2; ++mi)
      #pragma unroll
      for (int sub = 0; sub < 4; ++sub)
        s[mi][sub] = (f32x4){0.f, 0.f, 0.f, 0.f};
    #pragma unroll
    for (int sub = 0; sub < 4; ++sub) {
      short8 k0 = *(const short8*)(Ks + (sub * 16 + l16) * 72 + quad * 8);
      short8 k1 = *(const short8*)(Ks + (sub * 16 + l16) * 72 + 32 + quad * 8);
      #pragma unroll
      for (int mi = 0; mi < 2; ++mi) {
        s[mi][sub] = __builtin_amdgcn_mfma_f32_16x16x32_bf16(qf[mi][0], k0, s[mi][sub], 0, 0, 0);
        s[mi][sub] = __builtin_amdgcn_mfma_f32_16x16x32_bf16(qf[mi][1], k1, s[mi][sub], 0, 0, 0);
      }
    }

    // softmax (no running max; scores bounded) + P write
    #pragma unroll
    for (int mi = 0; mi < 2; ++mi)
      #pragma unroll
      for (int sub = 0; sub < 4; ++sub) {
        int key = kv0 + sub * 16 + l16;
        #pragma unroll
        for (int r = 0; r < 4; ++r) {
          float v = s[mi][sub][r] * 0.180336881f;  // *scale*log2(e)
          if (bias_wave && mi == 0 && quad == 0 && r == 0 && key >= 1 && key < N_)
            v += seg_bias[b * (N_ - 1) + key - 1] * ss;
          float p = exp2f(v);
          if (key >= N_) p = 0.f;
          lsum[mi][r] += p;
          pw[(mi * 16 + quad * 4 + r) * 72 + sub * 16 + l16] = f2bf(p);
        }
      }

    // PV (P write->read is same-wave: LDS ops per-wave in order)
    #pragma unroll
    for (int mi = 0; mi < 2; ++mi) {
      short8 pa0 = *(const short8*)(pw + (mi * 16 + l16) * 72 + quad * 8);
      short8 pa1 = *(const short8*)(pw + (mi * 16 + l16) * 72 + 32 + quad * 8);
      #pragma unroll
      for (int ds = 0; ds < 4; ++ds) {
        short8 vb0 = *(const short8*)(Vt + (ds * 16 + l16) * 72 + quad * 8);
        short8 vb1 = *(const short8*)(Vt + (ds * 16 + l16) * 72 + 32 + quad * 8);
        o[mi][ds] = __builtin_amdgcn_mfma_f32_16x16x32_bf16(pa0, vb0, o[mi][ds], 0, 0, 0);
        o[mi][ds] = __builtin_amdgcn_mfma_f32_16x16x32_bf16(pa1, vb1, o[mi][ds], 0, 0, 0);
      }
    }
  }

  // epilogue
  #pragma unroll
  for (int mi = 0; mi < 2; ++mi)
    #pragma unroll
    for (int r = 0; r < 4; ++r) {
      float l = lsum[mi][r];
      #pragma unroll
      for (int off = 1; off < 16; off <<= 1)
        l += __shfl_xor(l, off);
      float inv = 1.0f / l;
      int row = q0 + mi * 16 + quad * 4 + r;
      if (row < N_) {
        size_t base = ((size_t)b * N_ + row) * HID_ + h * HD_;
        #pragma unroll
        for (int ds = 0; ds < 4; ++ds)
          out[base + ds * 16 + l16] = f2bf(o[mi][ds][r] * inv);
      }
    }
}

// ---------------------------------------------------------------------------
// ws layout (bytes):
//   xb     bf16[BN*768]     @ 0            (28,360,704)  -- reused as attnb
//   wqkvT  bf16[2304*768]   @ 28,360,704   ( 3,538,944)
//   wprojT bf16[768*768]    @ 31,899,648   ( 1,179,648)
//   qkvb   bf16[BN*2304]    @ 33,079,296   (85,082,112)
//   vT     bf16[384*64*640] @ 118,161,408  (31,457,280)
//   total 149,618,688 B
// ---------------------------------------------------------------------------
extern "C" void kernel_launch(void* const* d_in, const int* in_sizes, int n_in,
                              void* d_out, int out_size, void* d_ws, size_t ws_size,
                              hipStream_t stream) {
  const float* x         = (const float*)d_in[0];
  const float* seg_bias  = (const float*)d_in[1];
  const float* w_qkv     = (const float*)d_in[2];
  const float* b_qkv     = (const float*)d_in[3];
  const float* w_proj    = (const float*)d_in[4];
  const float* b_proj    = (const float*)d_in[5];
  const float* seg_scale = (const float*)d_in[6];

  char* ws = (char*)d_ws;
  bf16_t* xb     = (bf16_t*)ws;
  bf16_t* wqkvT  = (bf16_t*)(ws + 28360704);
  bf16_t* wprojT = (bf16_t*)(ws + 31899648);
  bf16_t* qkvb   = (bf16_t*)(ws + 33079296);
  bf16_t* vT     = (bf16_t*)(ws + 118161408);
  bf16_t* attnb  = xb;

  cast_kernel<<<(BN_ * HID_ / 4) / 256, 256, 0, stream>>>(x, xb, BN_ * HID_ / 4);
  dim3 tb(32, 8);
  transpose_cast_kernel<<<dim3(QKVC_ / 32, HID_ / 32), tb, 0, stream>>>(w_qkv, wqkvT, HID_, QKVC_);
  transpose_cast_kernel<<<dim3(HID_ / 32, HID_ / 32), tb, 0, stream>>>(w_proj, wprojT, HID_, HID_);

  gemm_bf16_kernel<1><<<dim3(145, QKVC_ / 128), 256, 0, stream>>>(
      xb, wqkvT, b_qkv, (void*)qkvb, BN_, QKVC_);

  vt_kernel<<<dim3(10, NH_, B_), 256, 0, stream>>>(qkvb, vT);

  attn_kernel<<<dim3(5, NH_, B_), 256, 0, stream>>>(qkvb, vT, seg_bias, seg_scale, attnb);

  gemm_bf16_kernel<0><<<dim3(145, HID_ / 128), 256, 0, stream>>>(
      attnb, wprojT, b_proj, d_out, BN_, HID_);
}

// Round 4
// 352.966 us; speedup vs baseline: 1.4996x; 1.1983x over previous
//
#include <hip/hip_runtime.h>

// ---------------------------------------------------------------------------
// SegAwareMultiHeadAttention on MI355X (gfx950)
// B=32, N=577, HIDDEN=768, HEADS=12, HEAD_DIM=64
// cast/transpose -> QKV GEMM (bf16 MFMA, BK=64 DMA staging, XCD-remapped) ->
// V-transpose prepass -> flash attention (Q-tile 128) -> proj GEMM
// ---------------------------------------------------------------------------

typedef unsigned short bf16_t;
typedef __attribute__((ext_vector_type(8))) short short8;   // 8 bf16 = 16 B
typedef __attribute__((ext_vector_type(4))) float f32x4;    // MFMA C/D frag

#define B_    32
#define N_    577
#define BN_   18464
#define HID_  768
#define NH_   12
#define HD_   64
#define QKVC_ 2304
#define NPAD_ 640     // keys padded to 10 tiles of 64

__device__ __forceinline__ bf16_t f2bf(float f) {
  union { float f; unsigned u; } x; x.f = f;
  unsigned r = x.u + 0x7fffu + ((x.u >> 16) & 1u);
  return (bf16_t)(r >> 16);
}

// ---------------------------------------------------------------------------
__global__ __launch_bounds__(256) void cast_kernel(const float* __restrict__ in,
                                                   bf16_t* __restrict__ out, int n4) {
  int i = blockIdx.x * 256 + threadIdx.x;
  if (i >= n4) return;
  float4 v = ((const float4*)in)[i];
  ushort4 o;
  o.x = f2bf(v.x); o.y = f2bf(v.y); o.z = f2bf(v.z); o.w = f2bf(v.w);
  ((ushort4*)out)[i] = o;
}

// in fp32 [R][C] -> out bf16 [C][R]
__global__ __launch_bounds__(256) void transpose_cast_kernel(const float* __restrict__ in,
                                                             bf16_t* __restrict__ out,
                                                             int R, int C) {
  __shared__ float tile[32][33];
  int c0 = blockIdx.x * 32, r0 = blockIdx.y * 32;
  int tx = threadIdx.x, ty = threadIdx.y;
  #pragma unroll
  for (int i = ty; i < 32; i += 8)
    tile[i][tx] = in[(size_t)(r0 + i) * C + c0 + tx];
  __syncthreads();
  #pragma unroll
  for (int i = ty; i < 32; i += 8)
    out[(size_t)(c0 + i) * R + r0 + tx] = f2bf(tile[tx][i]);
}

// ---------------------------------------------------------------------------
// GEMM: C[M][Nc] = A[M][768] * Bt[Nc][768]^T + bias. 128x128 tile, BK=64
// (12 barriers for K=768). Staging via global_load_lds width=16.
// Source-side XOR swizzle: lane reads global chunk ch = chp ^ (row&7), writes
// LDS lane-linear; frag reads XOR the same pattern -> 2-way banks (free).
// Block remap: 8 consecutive blocks = 8 m-strips x same n (XCD round-robin
// keeps one 196KB A-strip hot per XCD L2 across all n-strips).
// ---------------------------------------------------------------------------
template <int OUT_BF16>
__global__ __launch_bounds__(256, 3) void gemm_bf16_kernel(
    const bf16_t* __restrict__ A,
    const bf16_t* __restrict__ Bt,
    const float* __restrict__ bias,
    void* __restrict__ Cout,
    int M, int Nc) {
  __shared__ bf16_t As[128 * 64];
  __shared__ bf16_t Bs[128 * 64];

  const int tid  = threadIdx.x;
  const int lane = tid & 63, w = tid >> 6;
  const int quad = lane >> 4, l16 = lane & 15;

  // ---- block remap: panels of 8 m-blocks, n fast within panel ----
  const int Mb = (M + 127) >> 7;            // 145
  const int Nb = Nc >> 7;                   // 18 or 6
  const int np_full = Mb >> 3;              // 18
  const int rem = Mb - np_full * 8;         // 1
  int bid = blockIdx.x;
  int m_blk, n_blk;
  int body = np_full * 8 * Nb;
  if (bid < body) {
    int p = bid / (8 * Nb), local = bid % (8 * Nb);
    m_blk = p * 8 + (local & 7);
    n_blk = local >> 3;
  } else {
    int t = bid - body;
    m_blk = np_full * 8 + t % rem;
    n_blk = t / rem;
  }
  const int m0 = m_blk * 128, n0 = n_blk * 128;
  const int wm = (w >> 1) * 64, wn = (w & 1) * 64;

  f32x4 acc[4][4];
  #pragma unroll
  for (int i = 0; i < 4; ++i)
    #pragma unroll
    for (int j = 0; j < 4; ++j)
      acc[i][j] = (f32x4){0.f, 0.f, 0.f, 0.f};

  for (int kt = 0; kt < 768; kt += 64) {
    __syncthreads();  // WAR: prior iteration's frag reads done
    #pragma unroll
    for (int it = 0; it < 4; ++it) {
      int gi = it * 256 + tid;
      int row = gi >> 3, chp = gi & 7;
      int ch = chp ^ (row & 7);
      int gm = m0 + row; if (gm >= M) gm = M - 1;  // dup rows, masked at epilogue
      __builtin_amdgcn_global_load_lds(
          (const __attribute__((address_space(1))) unsigned int*)(A + (size_t)gm * 768 + kt + ch * 8),
          (__attribute__((address_space(3))) unsigned int*)(As + gi * 8),
          16, 0, 0);
      int gn = n0 + row;  // Nc multiple of 128: always valid
      __builtin_amdgcn_global_load_lds(
          (const __attribute__((address_space(1))) unsigned int*)(Bt + (size_t)gn * 768 + kt + ch * 8),
          (__attribute__((address_space(3))) unsigned int*)(Bs + gi * 8),
          16, 0, 0);
    }
    __syncthreads();  // includes vmcnt(0) drain of the DMA

    #pragma unroll
    for (int ks = 0; ks < 2; ++ks) {
      short8 af[4], bfr[4];
      #pragma unroll
      for (int i = 0; i < 4; ++i) {
        int row = wm + i * 16 + l16;
        int c = ks * 4 + quad;
        af[i] = *(const short8*)(As + row * 64 + (c ^ (row & 7)) * 8);
      }
      #pragma unroll
      for (int j = 0; j < 4; ++j) {
        int row = wn + j * 16 + l16;
        int c = ks * 4 + quad;
        bfr[j] = *(const short8*)(Bs + row * 64 + (c ^ (row & 7)) * 8);
      }
      #pragma unroll
      for (int i = 0; i < 4; ++i)
        #pragma unroll
        for (int j = 0; j < 4; ++j)
          acc[i][j] = __builtin_amdgcn_mfma_f32_16x16x32_bf16(af[i], bfr[j], acc[i][j], 0, 0, 0);
    }
  }

  // epilogue: C layout col=lane&15, row=quad*4+reg
  #pragma unroll
  for (int i = 0; i < 4; ++i) {
    int mrow_base = m0 + wm + i * 16 + quad * 4;
    #pragma unroll
    for (int j = 0; j < 4; ++j) {
      int col = n0 + wn + j * 16 + l16;
      float bs = bias[col];
      #pragma unroll
      for (int r = 0; r < 4; ++r) {
        int row = mrow_base + r;
        if (row < M) {
          float v = acc[i][j][r] + bs;
          if (OUT_BF16)
            ((bf16_t*)Cout)[(size_t)row * Nc + col] = f2bf(v);
          else
            ((float*)Cout)[(size_t)row * Nc + col] = v;
        }
      }
    }
  }
}

// ---------------------------------------------------------------------------
// V transpose prepass: qkv V-slice [key][d] -> vT[bh][d=64][NPAD_ keys]
// ---------------------------------------------------------------------------
__global__ __launch_bounds__(256) void vt_kernel(const bf16_t* __restrict__ qkv,
                                                 bf16_t* __restrict__ vT) {
  const int t = blockIdx.x, h = blockIdx.y, b = blockIdx.z;
  const int tid = threadIdx.x;
  __shared__ bf16_t Ls[64 * 65];
  const int kv0 = t * 64;
  const bf16_t* Vp = qkv + (size_t)b * N_ * QKVC_ + 2 * HID_ + h * HD_;

  #pragma unroll
  for (int it = 0; it < 2; ++it) {
    int idx = it * 256 + tid;
    int row = idx >> 3, ch = idx & 7;
    int krow = kv0 + row; if (krow > N_ - 1) krow = N_ - 1;
    short8 v8 = *(const short8*)(Vp + (size_t)krow * QKVC_ + ch * 8);
    #pragma unroll
    for (int j = 0; j < 8; ++j)
      Ls[(ch * 8 + j) * 65 + row] = (bf16_t)v8[j];
  }
  __syncthreads();
  bf16_t* outp = vT + ((size_t)(b * NH_ + h) * HD_) * NPAD_;
  #pragma unroll
  for (int it = 0; it < 2; ++it) {
    int idx = it * 256 + tid;
    int d = idx >> 3, kc = idx & 7;
    short8 o8;
    #pragma unroll
    for (int j = 0; j < 8; ++j)
      o8[j] = (short)Ls[d * 65 + kc * 8 + j];
    *(short8*)(outp + (size_t)d * NPAD_ + kv0 + kc * 8) = o8;
  }
}

// ---------------------------------------------------------------------------
// Flash attention v2. Block = (q-tile 128, head, batch), 4 waves x 32 q-rows.
// KV tile 64. LDS: Ks[64][72], Vt[64][72] ([d][key]), P per-wave [32][72].
// Max-free softmax (scores bounded): no shuffles in loop, l-reduce at end.
// ---------------------------------------------------------------------------
__global__ __launch_bounds__(256) void attn_kernel(
    const bf16_t* __restrict__ qkv,       // [BN][2304]
    const bf16_t* __restrict__ vT,        // [bh][64][NPAD_]
    const float* __restrict__ seg_bias,   // [B][576]
    const float* __restrict__ seg_scale,  // [1]
    bf16_t* __restrict__ out) {           // [BN][768]
  const int qt = blockIdx.x;   // 0..4
  const int h  = blockIdx.y;
  const int b  = blockIdx.z;
  const int tid = threadIdx.x;
  const int w = tid >> 6, lane = tid & 63;
  const int quad = lane >> 4, l16 = lane & 15;

  __shared__ bf16_t Ks[64 * 72];
  __shared__ bf16_t Vt[64 * 72];
  __shared__ bf16_t Pb[4][32 * 72];

  const bf16_t* Qbase = qkv + (size_t)b * N_ * QKVC_ + h * HD_;
  const bf16_t* Kbase = Qbase + HID_;
  const bf16_t* Vtb   = vT + ((size_t)(b * NH_ + h) * HD_) * NPAD_;

  const int q0 = qt * 128 + w * 32;
  short8 qf[2][2];
  #pragma unroll
  for (int mi = 0; mi < 2; ++mi) {
    int qr = q0 + mi * 16 + l16;
    if (qr > N_ - 1) qr = N_ - 1;
    qf[mi][0] = *(const short8*)(Qbase + (size_t)qr * QKVC_ + quad * 8);
    qf[mi][1] = *(const short8*)(Qbase + (size_t)qr * QKVC_ + 32 + quad * 8);
  }

  f32x4 o[2][4];
  float lsum[2][4];
  #pragma unroll
  for (int mi = 0; mi < 2; ++mi)
    #pragma unroll
    for (int j = 0; j < 4; ++j) {
      o[mi][j] = (f32x4){0.f, 0.f, 0.f, 0.f};
      lsum[mi][j] = 0.f;
    }

  const float ss = seg_scale[0] * 1.44269504f;
  const bool bias_wave = (qt == 0 && w == 0);
  bf16_t* pw = Pb[w];

  for (int t = 0; t < 10; ++t) {
    const int kv0 = t * 64;
    __syncthreads();  // prior tile's LDS reads done
    #pragma unroll
    for (int it = 0; it < 2; ++it) {
      int idx = it * 256 + tid;
      int row = idx >> 3, ch = idx & 7;
      int krow = kv0 + row; if (krow > N_ - 1) krow = N_ - 1;
      short8 k8 = *(const short8*)(Kbase + (size_t)krow * QKVC_ + ch * 8);
      *(short8*)(Ks + row * 72 + ch * 8) = k8;
      short8 v8 = *(const short8*)(Vtb + (size_t)row * NPAD_ + kv0 + ch * 8);
      *(short8*)(Vt + row * 72 + ch * 8) = v8;
    }
    __syncthreads();

    // S = Q K^T
    f32x4 s[2][4];
    #pragma unroll
    for (int mi = 0; mi < 2; ++mi)
      #pragma unroll
      for (int sub = 0; sub < 4; ++sub)
        s[mi][sub] = (f32x4){0.f, 0.f, 0.f, 0.f};
    #pragma unroll
    for (int sub = 0; sub < 4; ++sub) {
      short8 k0 = *(const short8*)(Ks + (sub * 16 + l16) * 72 + quad * 8);
      short8 k1 = *(const short8*)(Ks + (sub * 16 + l16) * 72 + 32 + quad * 8);
      #pragma unroll
      for (int mi = 0; mi < 2; ++mi) {
        s[mi][sub] = __builtin_amdgcn_mfma_f32_16x16x32_bf16(qf[mi][0], k0, s[mi][sub], 0, 0, 0);
        s[mi][sub] = __builtin_amdgcn_mfma_f32_16x16x32_bf16(qf[mi][1], k1, s[mi][sub], 0, 0, 0);
      }
    }

    // softmax (no running max; scores bounded) + P write
    #pragma unroll
    for (int mi = 0; mi < 2; ++mi)
      #pragma unroll
      for (int sub = 0; sub < 4; ++sub) {
        int key = kv0 + sub * 16 + l16;
        #pragma unroll
        for (int r = 0; r < 4; ++r) {
          float v = s[mi][sub][r] * 0.180336881f;  // *scale*log2(e)
          if (bias_wave && mi == 0 && quad == 0 && r == 0 && key >= 1 && key < N_)
            v += seg_bias[b * (N_ - 1) + key - 1] * ss;
          float p = exp2f(v);
          if (key >= N_) p = 0.f;
          lsum[mi][r] += p;
          pw[(mi * 16 + quad * 4 + r) * 72 + sub * 16 + l16] = f2bf(p);
        }
      }

    // PV (P write->read is same-wave: LDS ops per-wave in order)
    #pragma unroll
    for (int mi = 0; mi < 2; ++mi) {
      short8 pa0 = *(const short8*)(pw + (mi * 16 + l16) * 72 + quad * 8);
      short8 pa1 = *(const short8*)(pw + (mi * 16 + l16) * 72 + 32 + quad * 8);
      #pragma unroll
      for (int ds = 0; ds < 4; ++ds) {
        short8 vb0 = *(const short8*)(Vt + (ds * 16 + l16) * 72 + quad * 8);
        short8 vb1 = *(const short8*)(Vt + (ds * 16 + l16) * 72 + 32 + quad * 8);
        o[mi][ds] = __builtin_amdgcn_mfma_f32_16x16x32_bf16(pa0, vb0, o[mi][ds], 0, 0, 0);
        o[mi][ds] = __builtin_amdgcn_mfma_f32_16x16x32_bf16(pa1, vb1, o[mi][ds], 0, 0, 0);
      }
    }
  }

  // epilogue
  #pragma unroll
  for (int mi = 0; mi < 2; ++mi)
    #pragma unroll
    for (int r = 0; r < 4; ++r) {
      float l = lsum[mi][r];
      #pragma unroll
      for (int off = 1; off < 16; off <<= 1)
        l += __shfl_xor(l, off);
      float inv = 1.0f / l;
      int row = q0 + mi * 16 + quad * 4 + r;
      if (row < N_) {
        size_t base = ((size_t)b * N_ + row) * HID_ + h * HD_;
        #pragma unroll
        for (int ds = 0; ds < 4; ++ds)
          out[base + ds * 16 + l16] = f2bf(o[mi][ds][r] * inv);
      }
    }
}

// ---------------------------------------------------------------------------
// ws layout (bytes):
//   xb     bf16[BN*768]     @ 0            (28,360,704)  -- reused as attnb
//   wqkvT  bf16[2304*768]   @ 28,360,704   ( 3,538,944)
//   wprojT bf16[768*768]    @ 31,899,648   ( 1,179,648)
//   qkvb   bf16[BN*2304]    @ 33,079,296   (85,082,112)
//   vT     bf16[384*64*640] @ 118,161,408  (31,457,280)
//   total 149,618,688 B
// ---------------------------------------------------------------------------
extern "C" void kernel_launch(void* const* d_in, const int* in_sizes, int n_in,
                              void* d_out, int out_size, void* d_ws, size_t ws_size,
                              hipStream_t stream) {
  const float* x         = (const float*)d_in[0];
  const float* seg_bias  = (const float*)d_in[1];
  const float* w_qkv     = (const float*)d_in[2];
  const float* b_qkv     = (const float*)d_in[3];
  const float* w_proj    = (const float*)d_in[4];
  const float* b_proj    = (const float*)d_in[5];
  const float* seg_scale = (const float*)d_in[6];

  char* ws = (char*)d_ws;
  bf16_t* xb     = (bf16_t*)ws;
  bf16_t* wqkvT  = (bf16_t*)(ws + 28360704);
  bf16_t* wprojT = (bf16_t*)(ws + 31899648);
  bf16_t* qkvb   = (bf16_t*)(ws + 33079296);
  bf16_t* vT     = (bf16_t*)(ws + 118161408);
  bf16_t* attnb  = xb;

  cast_kernel<<<(BN_ * HID_ / 4) / 256, 256, 0, stream>>>(x, xb, BN_ * HID_ / 4);
  dim3 tb(32, 8);
  transpose_cast_kernel<<<dim3(QKVC_ / 32, HID_ / 32), tb, 0, stream>>>(w_qkv, wqkvT, HID_, QKVC_);
  transpose_cast_kernel<<<dim3(HID_ / 32, HID_ / 32), tb, 0, stream>>>(w_proj, wprojT, HID_, HID_);

  gemm_bf16_kernel<1><<<145 * (QKVC_ / 128), 256, 0, stream>>>(
      xb, wqkvT, b_qkv, (void*)qkvb, BN_, QKVC_);

  vt_kernel<<<dim3(10, NH_, B_), 256, 0, stream>>>(qkvb, vT);

  attn_kernel<<<dim3(5, NH_, B_), 256, 0, stream>>>(qkvb, vT, seg_bias, seg_scale, attnb);

  gemm_bf16_kernel<0><<<145 * (HID_ / 128), 256, 0, stream>>>(
      attnb, wprojT, b_proj, d_out, BN_, HID_);
}

// Round 5
// 342.113 us; speedup vs baseline: 1.5472x; 1.0317x over previous
//
#include <hip/hip_runtime.h>

// ---------------------------------------------------------------------------
// SegAwareMultiHeadAttention on MI355X (gfx950)
// B=32, N=577, HIDDEN=768, HEADS=12, HEAD_DIM=64
// cast/transpose -> QKV GEMM (bf16 MFMA, BK=64 DMA staging, XCD-remapped) ->
// V-transpose prepass -> flash attention v3 (dbuf, 1 barrier/tile) -> proj GEMM
// ---------------------------------------------------------------------------

typedef unsigned short bf16_t;
typedef __attribute__((ext_vector_type(8))) short short8;   // 8 bf16 = 16 B
typedef __attribute__((ext_vector_type(4))) float f32x4;    // MFMA C/D frag

#define B_    32
#define N_    577
#define BN_   18464
#define HID_  768
#define NH_   12
#define HD_   64
#define QKVC_ 2304
#define NPAD_ 640     // keys padded to 10 tiles of 64

__device__ __forceinline__ bf16_t f2bf(float f) {
  union { float f; unsigned u; } x; x.f = f;
  unsigned r = x.u + 0x7fffu + ((x.u >> 16) & 1u);
  return (bf16_t)(r >> 16);
}

// ---------------------------------------------------------------------------
__global__ __launch_bounds__(256) void cast_kernel(const float* __restrict__ in,
                                                   bf16_t* __restrict__ out, int n4) {
  int i = blockIdx.x * 256 + threadIdx.x;
  if (i >= n4) return;
  float4 v = ((const float4*)in)[i];
  ushort4 o;
  o.x = f2bf(v.x); o.y = f2bf(v.y); o.z = f2bf(v.z); o.w = f2bf(v.w);
  ((ushort4*)out)[i] = o;
}

// in fp32 [R][C] -> out bf16 [C][R]
__global__ __launch_bounds__(256) void transpose_cast_kernel(const float* __restrict__ in,
                                                             bf16_t* __restrict__ out,
                                                             int R, int C) {
  __shared__ float tile[32][33];
  int c0 = blockIdx.x * 32, r0 = blockIdx.y * 32;
  int tx = threadIdx.x, ty = threadIdx.y;
  #pragma unroll
  for (int i = ty; i < 32; i += 8)
    tile[i][tx] = in[(size_t)(r0 + i) * C + c0 + tx];
  __syncthreads();
  #pragma unroll
  for (int i = ty; i < 32; i += 8)
    out[(size_t)(c0 + i) * R + r0 + tx] = f2bf(tile[tx][i]);
}

// ---------------------------------------------------------------------------
// GEMM: C[M][Nc] = A[M][768] * Bt[Nc][768]^T + bias. 128x128 tile, BK=64.
// global_load_lds width=16 staging, source-side XOR swizzle, panel remap.
// (unchanged from round 4 — 0 bank conflicts, panel remap keeps A-strip in L2)
// ---------------------------------------------------------------------------
template <int OUT_BF16>
__global__ __launch_bounds__(256, 3) void gemm_bf16_kernel(
    const bf16_t* __restrict__ A,
    const bf16_t* __restrict__ Bt,
    const float* __restrict__ bias,
    void* __restrict__ Cout,
    int M, int Nc) {
  __shared__ bf16_t As[128 * 64];
  __shared__ bf16_t Bs[128 * 64];

  const int tid  = threadIdx.x;
  const int lane = tid & 63, w = tid >> 6;
  const int quad = lane >> 4, l16 = lane & 15;

  const int Mb = (M + 127) >> 7;
  const int Nb = Nc >> 7;
  const int np_full = Mb >> 3;
  const int rem = Mb - np_full * 8;
  int bid = blockIdx.x;
  int m_blk, n_blk;
  int body = np_full * 8 * Nb;
  if (bid < body) {
    int p = bid / (8 * Nb), local = bid % (8 * Nb);
    m_blk = p * 8 + (local & 7);
    n_blk = local >> 3;
  } else {
    int t = bid - body;
    m_blk = np_full * 8 + t % rem;
    n_blk = t / rem;
  }
  const int m0 = m_blk * 128, n0 = n_blk * 128;
  const int wm = (w >> 1) * 64, wn = (w & 1) * 64;

  f32x4 acc[4][4];
  #pragma unroll
  for (int i = 0; i < 4; ++i)
    #pragma unroll
    for (int j = 0; j < 4; ++j)
      acc[i][j] = (f32x4){0.f, 0.f, 0.f, 0.f};

  for (int kt = 0; kt < 768; kt += 64) {
    __syncthreads();
    #pragma unroll
    for (int it = 0; it < 4; ++it) {
      int gi = it * 256 + tid;
      int row = gi >> 3, chp = gi & 7;
      int ch = chp ^ (row & 7);
      int gm = m0 + row; if (gm >= M) gm = M - 1;
      __builtin_amdgcn_global_load_lds(
          (const __attribute__((address_space(1))) unsigned int*)(A + (size_t)gm * 768 + kt + ch * 8),
          (__attribute__((address_space(3))) unsigned int*)(As + gi * 8),
          16, 0, 0);
      int gn = n0 + row;
      __builtin_amdgcn_global_load_lds(
          (const __attribute__((address_space(1))) unsigned int*)(Bt + (size_t)gn * 768 + kt + ch * 8),
          (__attribute__((address_space(3))) unsigned int*)(Bs + gi * 8),
          16, 0, 0);
    }
    __syncthreads();

    #pragma unroll
    for (int ks = 0; ks < 2; ++ks) {
      short8 af[4], bfr[4];
      #pragma unroll
      for (int i = 0; i < 4; ++i) {
        int row = wm + i * 16 + l16;
        int c = ks * 4 + quad;
        af[i] = *(const short8*)(As + row * 64 + (c ^ (row & 7)) * 8);
      }
      #pragma unroll
      for (int j = 0; j < 4; ++j) {
        int row = wn + j * 16 + l16;
        int c = ks * 4 + quad;
        bfr[j] = *(const short8*)(Bs + row * 64 + (c ^ (row & 7)) * 8);
      }
      #pragma unroll
      for (int i = 0; i < 4; ++i)
        #pragma unroll
        for (int j = 0; j < 4; ++j)
          acc[i][j] = __builtin_amdgcn_mfma_f32_16x16x32_bf16(af[i], bfr[j], acc[i][j], 0, 0, 0);
    }
  }

  #pragma unroll
  for (int i = 0; i < 4; ++i) {
    int mrow_base = m0 + wm + i * 16 + quad * 4;
    #pragma unroll
    for (int j = 0; j < 4; ++j) {
      int col = n0 + wn + j * 16 + l16;
      float bs = bias[col];
      #pragma unroll
      for (int r = 0; r < 4; ++r) {
        int row = mrow_base + r;
        if (row < M) {
          float v = acc[i][j][r] + bs;
          if (OUT_BF16)
            ((bf16_t*)Cout)[(size_t)row * Nc + col] = f2bf(v);
          else
            ((float*)Cout)[(size_t)row * Nc + col] = v;
        }
      }
    }
  }
}

// ---------------------------------------------------------------------------
// V transpose prepass: qkv V-slice [key][d] -> vT[bh][d=64][NPAD_ keys]
// ---------------------------------------------------------------------------
__global__ __launch_bounds__(256) void vt_kernel(const bf16_t* __restrict__ qkv,
                                                 bf16_t* __restrict__ vT) {
  const int t = blockIdx.x, h = blockIdx.y, b = blockIdx.z;
  const int tid = threadIdx.x;
  __shared__ bf16_t Ls[64 * 65];
  const int kv0 = t * 64;
  const bf16_t* Vp = qkv + (size_t)b * N_ * QKVC_ + 2 * HID_ + h * HD_;

  #pragma unroll
  for (int it = 0; it < 2; ++it) {
    int idx = it * 256 + tid;
    int row = idx >> 3, ch = idx & 7;
    int krow = kv0 + row; if (krow > N_ - 1) krow = N_ - 1;
    short8 v8 = *(const short8*)(Vp + (size_t)krow * QKVC_ + ch * 8);
    #pragma unroll
    for (int j = 0; j < 8; ++j)
      Ls[(ch * 8 + j) * 65 + row] = (bf16_t)v8[j];
  }
  __syncthreads();
  bf16_t* outp = vT + ((size_t)(b * NH_ + h) * HD_) * NPAD_;
  #pragma unroll
  for (int it = 0; it < 2; ++it) {
    int idx = it * 256 + tid;
    int d = idx >> 3, kc = idx & 7;
    short8 o8;
    #pragma unroll
    for (int j = 0; j < 8; ++j)
      o8[j] = (short)Ls[d * 65 + kc * 8 + j];
    *(short8*)(outp + (size_t)d * NPAD_ + kv0 + kc * 8) = o8;
  }
}

// ---------------------------------------------------------------------------
// Flash attention v3. Flat grid 1920: pair = bid%384 (b,h), qt = bid/384 so
// all 5 q-tiles of a pair land on one XCD (384 % 8 == 0) -> K/V L2-resident.
// Double-buffered K/V tiles, ONE barrier per tile (prefetch regs -> LDS).
// VALU diet: scale*log2e folded into Q frags; mask only in last tile;
// P stored via +0x8000 round-half-up; P rows permuted (phys = r*4+quad)
// so the 4 quads' u16 writes hit disjoint bank windows.
// ---------------------------------------------------------------------------
__global__ __launch_bounds__(256) void attn_kernel(
    const bf16_t* __restrict__ qkv,       // [BN][2304]
    const bf16_t* __restrict__ vT,        // [bh][64][NPAD_]
    const float* __restrict__ seg_bias,   // [B][576]
    const float* __restrict__ seg_scale,  // [1]
    bf16_t* __restrict__ out) {           // [BN][768]
  const int bid  = blockIdx.x;
  const int pair = bid % (B_ * NH_);
  const int qt   = bid / (B_ * NH_);     // 0..4
  const int h    = pair % NH_;
  const int b    = pair / NH_;
  const int tid = threadIdx.x;
  const int w = tid >> 6, lane = tid & 63;
  const int quad = lane >> 4, l16 = lane & 15;

  __shared__ bf16_t Ks[2][64 * 72];
  __shared__ bf16_t Vt[2][64 * 72];
  __shared__ bf16_t Pb[4][32 * 72];

  const bf16_t* Qbase = qkv + (size_t)b * N_ * QKVC_ + h * HD_;
  const bf16_t* Kbase = Qbase + HID_;
  const bf16_t* Vtb   = vT + ((size_t)(b * NH_ + h) * HD_) * NPAD_;

  const int q0 = qt * 128 + w * 32;
  short8 qf[2][2];
  #pragma unroll
  for (int mi = 0; mi < 2; ++mi) {
    int qr = q0 + mi * 16 + l16;
    if (qr > N_ - 1) qr = N_ - 1;
    qf[mi][0] = *(const short8*)(Qbase + (size_t)qr * QKVC_ + quad * 8);
    qf[mi][1] = *(const short8*)(Qbase + (size_t)qr * QKVC_ + 32 + quad * 8);
  }
  // fold scale*log2(e) into Q (one extra bf16 rounding on Q, negligible)
  const float qsc = 0.125f * 1.44269504f;
  #pragma unroll
  for (int mi = 0; mi < 2; ++mi)
    #pragma unroll
    for (int c = 0; c < 2; ++c)
      #pragma unroll
      for (int j = 0; j < 8; ++j) {
        unsigned u = ((unsigned)(unsigned short)qf[mi][c][j]) << 16;
        union { unsigned u; float f; } x; x.u = u;
        qf[mi][c][j] = (short)f2bf(x.f * qsc);
      }

  f32x4 o[2][4];
  float lsum[2][4];
  #pragma unroll
  for (int mi = 0; mi < 2; ++mi)
    #pragma unroll
    for (int j = 0; j < 4; ++j) {
      o[mi][j] = (f32x4){0.f, 0.f, 0.f, 0.f};
      lsum[mi][j] = 0.f;
    }

  const float ssl = seg_scale[0] * 1.44269504f;
  const bool bias_wave = (qt == 0 && w == 0);
  bf16_t* pw = Pb[w];

  // staging geometry: 512 granules = 64 rows x 8 chunks, 2 per thread
  const int srow = tid >> 3;          // 0..31 (it adds +32)
  const int sch  = tid & 7;

  // preload tile 0
  short8 kpre[2], vpre[2];
  #pragma unroll
  for (int it = 0; it < 2; ++it) {
    int row = it * 32 + srow;
    int krow = row; if (krow > N_ - 1) krow = N_ - 1;
    kpre[it] = *(const short8*)(Kbase + (size_t)krow * QKVC_ + sch * 8);
    vpre[it] = *(const short8*)(Vtb + (size_t)row * NPAD_ + sch * 8);
  }
  #pragma unroll
  for (int it = 0; it < 2; ++it) {
    int row = it * 32 + srow;
    *(short8*)(&Ks[0][0] + row * 72 + sch * 8) = kpre[it];
    *(short8*)(&Vt[0][0] + row * 72 + sch * 8) = vpre[it];
  }
  __syncthreads();

  for (int t = 0; t < 10; ++t) {
    const int cur = t & 1;
    const int kv0 = t * 64;
    const bf16_t* ks = &Ks[cur][0];
    const bf16_t* vt = &Vt[cur][0];

    // issue prefetch for t+1 (latency hidden behind compute below)
    if (t < 9) {
      const int kv1 = kv0 + 64;
      #pragma unroll
      for (int it = 0; it < 2; ++it) {
        int row = it * 32 + srow;
        int krow = kv1 + row; if (krow > N_ - 1) krow = N_ - 1;
        kpre[it] = *(const short8*)(Kbase + (size_t)krow * QKVC_ + sch * 8);
        vpre[it] = *(const short8*)(Vtb + (size_t)row * NPAD_ + kv1 + sch * 8);
      }
    }

    // S = Q K^T (logits already in log2 domain via Q scaling)
    f32x4 s[2][4];
    #pragma unroll
    for (int mi = 0; mi < 2; ++mi)
      #pragma unroll
      for (int sub = 0; sub < 4; ++sub)
        s[mi][sub] = (f32x4){0.f, 0.f, 0.f, 0.f};
    #pragma unroll
    for (int sub = 0; sub < 4; ++sub) {
      short8 k0 = *(const short8*)(ks + (sub * 16 + l16) * 72 + quad * 8);
      short8 k1 = *(const short8*)(ks + (sub * 16 + l16) * 72 + 32 + quad * 8);
      #pragma unroll
      for (int mi = 0; mi < 2; ++mi) {
        s[mi][sub] = __builtin_amdgcn_mfma_f32_16x16x32_bf16(qf[mi][0], k0, s[mi][sub], 0, 0, 0);
        s[mi][sub] = __builtin_amdgcn_mfma_f32_16x16x32_bf16(qf[mi][1], k1, s[mi][sub], 0, 0, 0);
      }
    }

    // rare CLS-row bias (divergent branch, one wave of one q-block)
    if (bias_wave && quad == 0) {
      #pragma unroll
      for (int sub = 0; sub < 4; ++sub) {
        int key = kv0 + sub * 16 + l16;
        if (key >= 1 && key < N_)
          s[0][sub][0] += seg_bias[b * (N_ - 1) + key - 1] * ssl;
      }
    }

    // softmax: p = exp2(s); mask only in (uniform) last tile; store round-half-up
    #pragma unroll
    for (int mi = 0; mi < 2; ++mi)
      #pragma unroll
      for (int sub = 0; sub < 4; ++sub) {
        #pragma unroll
        for (int r = 0; r < 4; ++r) {
          float p = exp2f(s[mi][sub][r]);
          if (t == 9) {
            int key = kv0 + sub * 16 + l16;
            if (key >= N_) p = 0.f;
          }
          lsum[mi][r] += p;
          union { float f; unsigned u; } c; c.f = p;
          pw[(mi * 16 + r * 4 + quad) * 72 + sub * 16 + l16] =
              (bf16_t)((c.u + 0x8000u) >> 16);
        }
      }

    // PV (P write->read same-wave: in-order LDS, no barrier needed)
    #pragma unroll
    for (int mi = 0; mi < 2; ++mi) {
      int prow = mi * 16 + ((l16 & 3) << 2) + (l16 >> 2);  // inverse of r*4+quad
      short8 pa0 = *(const short8*)(pw + prow * 72 + quad * 8);
      short8 pa1 = *(const short8*)(pw + prow * 72 + 32 + quad * 8);
      #pragma unroll
      for (int ds = 0; ds < 4; ++ds) {
        short8 vb0 = *(const short8*)(vt + (ds * 16 + l16) * 72 + quad * 8);
        short8 vb1 = *(const short8*)(vt + (ds * 16 + l16) * 72 + 32 + quad * 8);
        o[mi][ds] = __builtin_amdgcn_mfma_f32_16x16x32_bf16(pa0, vb0, o[mi][ds], 0, 0, 0);
        o[mi][ds] = __builtin_amdgcn_mfma_f32_16x16x32_bf16(pa1, vb1, o[mi][ds], 0, 0, 0);
      }
    }

    // write prefetch to the other buffer; single barrier covers RAW + WAR
    if (t < 9) {
      bf16_t* ksn = &Ks[1 - cur][0];
      bf16_t* vtn = &Vt[1 - cur][0];
      #pragma unroll
      for (int it = 0; it < 2; ++it) {
        int row = it * 32 + srow;
        *(short8*)(ksn + row * 72 + sch * 8) = kpre[it];
        *(short8*)(vtn + row * 72 + sch * 8) = vpre[it];
      }
    }
    __syncthreads();
  }

  // epilogue: normalize and store (P rounding vs exact lsum: same as prior rounds)
  #pragma unroll
  for (int mi = 0; mi < 2; ++mi)
    #pragma unroll
    for (int r = 0; r < 4; ++r) {
      float l = lsum[mi][r];
      #pragma unroll
      for (int off = 1; off < 16; off <<= 1)
        l += __shfl_xor(l, off);
      float inv = 1.0f / l;
      int row = q0 + mi * 16 + quad * 4 + r;
      if (row < N_) {
        size_t base = ((size_t)b * N_ + row) * HID_ + h * HD_;
        #pragma unroll
        for (int ds = 0; ds < 4; ++ds)
          out[base + ds * 16 + l16] = f2bf(o[mi][ds][r] * inv);
      }
    }
}

// ---------------------------------------------------------------------------
// ws layout (bytes):
//   xb     bf16[BN*768]     @ 0            (28,360,704)  -- reused as attnb
//   wqkvT  bf16[2304*768]   @ 28,360,704   ( 3,538,944)
//   wprojT bf16[768*768]    @ 31,899,648   ( 1,179,648)
//   qkvb   bf16[BN*2304]    @ 33,079,296   (85,082,112)
//   vT     bf16[384*64*640] @ 118,161,408  (31,457,280)
//   total 149,618,688 B
// ---------------------------------------------------------------------------
extern "C" void kernel_launch(void* const* d_in, const int* in_sizes, int n_in,
                              void* d_out, int out_size, void* d_ws, size_t ws_size,
                              hipStream_t stream) {
  const float* x         = (const float*)d_in[0];
  const float* seg_bias  = (const float*)d_in[1];
  const float* w_qkv     = (const float*)d_in[2];
  const float* b_qkv     = (const float*)d_in[3];
  const float* w_proj    = (const float*)d_in[4];
  const float* b_proj    = (const float*)d_in[5];
  const float* seg_scale = (const float*)d_in[6];

  char* ws = (char*)d_ws;
  bf16_t* xb     = (bf16_t*)ws;
  bf16_t* wqkvT  = (bf16_t*)(ws + 28360704);
  bf16_t* wprojT = (bf16_t*)(ws + 31899648);
  bf16_t* qkvb   = (bf16_t*)(ws + 33079296);
  bf16_t* vT     = (bf16_t*)(ws + 118161408);
  bf16_t* attnb  = xb;

  cast_kernel<<<(BN_ * HID_ / 4) / 256, 256, 0, stream>>>(x, xb, BN_ * HID_ / 4);
  dim3 tb(32, 8);
  transpose_cast_kernel<<<dim3(QKVC_ / 32, HID_ / 32), tb, 0, stream>>>(w_qkv, wqkvT, HID_, QKVC_);
  transpose_cast_kernel<<<dim3(HID_ / 32, HID_ / 32), tb, 0, stream>>>(w_proj, wprojT, HID_, HID_);

  gemm_bf16_kernel<1><<<145 * (QKVC_ / 128), 256, 0, stream>>>(
      xb, wqkvT, b_qkv, (void*)qkvb, BN_, QKVC_);

  vt_kernel<<<dim3(10, NH_, B_), 256, 0, stream>>>(qkvb, vT);

  attn_kernel<<<5 * NH_ * B_, 256, 0, stream>>>(qkvb, vT, seg_bias, seg_scale, attnb);

  gemm_bf16_kernel<0><<<145 * (HID_ / 128), 256, 0, stream>>>(
      attnb, wprojT, b_proj, d_out, BN_, HID_);
}